// Round 4
// baseline (323.024 us; speedup 1.0000x reference)
//
#include <hip/hip_runtime.h>
#include <stdint.h>
#include <stddef.h>

#define M_DIM 2048
#define N_DIM 4096
#define K_DIM 4352
#define H_DIM 1024
#define X_DIM 2304

// workspace layout (bytes)
#define A_OFF 0u
#define B_OFF 17825792u                 // 2048*4352*2

typedef __bf16 bf16x8 __attribute__((ext_vector_type(8)));
typedef float f32x4 __attribute__((ext_vector_type(4)));

__device__ __forceinline__ unsigned short f32_to_bf16(float f) {
    unsigned u = __float_as_uint(f);
    u += 0x7FFFu + ((u >> 16) & 1u);     // round-to-nearest-even
    return (unsigned short)(u >> 16);
}

__device__ __forceinline__ float sigm_(float x) { return 1.f / (1.f + __expf(-x)); }
__device__ __forceinline__ float tanh_(float x) {
    x = fminf(15.f, fmaxf(-15.f, x));
    float e = __expf(2.f * x);
    return (e - 1.f) / (e + 1.f);
}

// ---------------------------------------------------------------------------
// Kernel 1: pack z = [x | prev_time | prev_layer] -> A (rows 0..2047) and
// W_all gate-INTERLEAVED -> B: source row n (g = n>>10, h = n&1023) goes to
// B row n' = h*4 + g. bf16, K-contiguous, 16B stores.
// ---------------------------------------------------------------------------
__global__ __launch_bounds__(256) void convert_kernel(
    const float* __restrict__ x, const float* __restrict__ pt,
    const float* __restrict__ pl,
    const float* __restrict__ Wi, const float* __restrict__ Wf,
    const float* __restrict__ Wo, const float* __restrict__ Ws,
    unsigned short* __restrict__ Abf, unsigned short* __restrict__ Bbf)
{
    const int row = blockIdx.x;                  // 0..6143
    const float* srow = nullptr;
    unsigned short* drow;
    if (row < M_DIM) {
        drow = Abf + (size_t)row * K_DIM;
    } else {
        int n = row - M_DIM;                      // 0..4095
        int g = n >> 10, h = n & 1023;
        const float* W = (g == 0) ? Wi : (g == 1) ? Wf : (g == 2) ? Wo : Ws;
        srow = W + (size_t)h * K_DIM;
        drow = Bbf + (size_t)(h * 4 + g) * K_DIM;
    }

    for (int c8 = threadIdx.x; c8 < K_DIM / 8; c8 += 256) {
        int col = c8 * 8;
        const float* s;
        if (row < M_DIM) {
            // boundaries 2304, 3328 are multiples of 8: chunks never straddle
            if (col < X_DIM)              s = x  + (size_t)row * X_DIM + col;
            else if (col < X_DIM + H_DIM) s = pt + (size_t)row * H_DIM + (col - X_DIM);
            else                          s = pl + (size_t)row * H_DIM + (col - X_DIM - H_DIM);
        } else {
            s = srow + col;
        }
        float4 v0 = ((const float4*)s)[0];
        float4 v1 = ((const float4*)s)[1];
        union { unsigned short h[8]; uint4 u; } r;
        r.h[0] = f32_to_bf16(v0.x); r.h[1] = f32_to_bf16(v0.y);
        r.h[2] = f32_to_bf16(v0.z); r.h[3] = f32_to_bf16(v0.w);
        r.h[4] = f32_to_bf16(v1.x); r.h[5] = f32_to_bf16(v1.y);
        r.h[6] = f32_to_bf16(v1.z); r.h[7] = f32_to_bf16(v1.w);
        *(uint4*)(drow + col) = r.u;
    }
}

// ---------------------------------------------------------------------------
// Kernel 2: fused GEMM + gates. 128x128 tile, BK=64, 4 waves, 64x64/wave.
// A: global_load_lds -> XOR-swizzled LDS (as round 3).
// B: streamed global->VGPR per fragment (16B contiguous per lane, L2-served);
//    loads for tile kt are issued before the staging barrier so the vmcnt(0)
//    drain covers them, and next-tile loads register-rename past current MFMAs.
// Epilogue fused via sP aliased over sA (LDS block = 38.9 KB).
// ---------------------------------------------------------------------------
__global__ __launch_bounds__(256) void gemm_fused(
    const unsigned short* __restrict__ A,   // [M_DIM, K_DIM] bf16
    const unsigned short* __restrict__ B,   // [N_DIM, K_DIM] bf16, gate-interleaved
    const float* __restrict__ old_state,    // [2048, 1024]
    const float* __restrict__ bi, const float* __restrict__ bfv,
    const float* __restrict__ bo, const float* __restrict__ bs,
    float* __restrict__ out)                // [2048, 1024]
{
    __shared__ __align__(16) char smem[128 * 76 * 4];   // 38912 B
    unsigned short* sA = (unsigned short*)smem;         // [128*64] during K-loop
    float*          sP = (float*)smem;                  // [128*76] during epilogue

    const int tid  = threadIdx.x;
    const int lane = tid & 63;
    const int wave = tid >> 6;              // 0..3
    const int wm = (wave >> 1) * 64;
    const int wn = (wave & 1) * 64;

    // XCD-aware decode: xcd b&7 owns n-tiles 4*xcd..4*xcd+3 (disjoint B sets)
    const int b   = blockIdx.x;             // 0..511
    const int xcd = b & 7;
    const int j   = b >> 3;                 // 0..63
    const int n0  = (xcd * 4 + (j & 3)) * 128;
    const int m0  = (j >> 2) * 128;

    // A staging: lane deposits 16B at slot (i*256 + wave*64 + lane);
    // logical row = i*32 + wave*8 + (lane>>3), swizzled source col:
    const int srow = wave * 8 + (lane >> 3);
    const int c8s  = ((lane & 7) ^ (lane >> 3)) * 8;

    // fragment coords: frag[m or n = lane&15][k = (lane>>4)*8 + t]
    const int fr  = lane & 15;
    const int sw  = fr & 7;                 // row-swizzle key for sA reads
    const int kb0 = lane >> 4;              // k-block base
    const int fk  = kb0 * 8;

    f32x4 acc[4][4];
#pragma unroll
    for (int i = 0; i < 4; ++i)
#pragma unroll
        for (int jj = 0; jj < 4; ++jj) acc[i][jj] = (f32x4){0.f, 0.f, 0.f, 0.f};

    const unsigned short* Aw = A + (size_t)(m0 + srow) * K_DIM + c8s;
    const bf16x8* Bp[4];
#pragma unroll
    for (int jj = 0; jj < 4; ++jj)
        Bp[jj] = (const bf16x8*)(B + (size_t)(n0 + wn + jj * 16 + fr) * K_DIM + fk);

    for (int kt = 0; kt < K_DIM; kt += 64) {
        const int k8 = kt >> 3;             // offset in 8-elem units
        // B fragments for THIS tile: issue before barriers, drain with staging
        bf16x8 b0[4], b1[4];
#pragma unroll
        for (int jj = 0; jj < 4; ++jj) {
            b0[jj] = Bp[jj][k8];            // kk = 0
            b1[jj] = Bp[jj][k8 + 4];        // kk = 32
        }

        __syncthreads();   // prior-tile sA readers done before overwrite
#pragma unroll
        for (int i = 0; i < 4; ++i) {
            __builtin_amdgcn_global_load_lds(
                (const __attribute__((address_space(1))) unsigned*)(Aw + (size_t)i * 32 * K_DIM + kt),
                (__attribute__((address_space(3))) unsigned*)(smem + i * 4096 + wave * 1024),
                16, 0, 0);
        }
        __syncthreads();   // vmcnt(0) drain: sA ready AND b0/b1 resident

#pragma unroll
        for (int kk = 0; kk < 64; kk += 32) {
            const int kb = kk / 8 + kb0;    // logical k-block 0..7
            bf16x8 af[4];
#pragma unroll
            for (int i = 0; i < 4; ++i) {
                const int ra = wm + i * 16 + fr;
                af[i] = *(const bf16x8*)(sA + (ra * 8 + (kb ^ sw)) * 8);
            }
            const bf16x8* bf_ = (kk == 0) ? b0 : b1;
#pragma unroll
            for (int i = 0; i < 4; ++i)
#pragma unroll
                for (int jj = 0; jj < 4; ++jj)
                    acc[i][jj] = __builtin_amdgcn_mfma_f32_16x16x32_bf16(
                        af[i], bf_[jj], acc[i][jj], 0, 0, 0);
        }
    }

    // ---- fused epilogue: two half-passes over n --------------------------
    // C/D layout: col = lane&15, row = (lane>>4)*4 + reg
    const int cw = lane & 15;
    const int rw = (lane >> 4) * 4;
    const int hl = tid & 15;                // h within pass
    const int rb = tid >> 4;                // 0..15

    for (int p = 0; p < 2; ++p) {
        __syncthreads();                    // K-loop sA readers / pass p-1 done
        if ((wave & 1) == p) {              // waves owning n-half p write
#pragma unroll
            for (int i = 0; i < 4; ++i)
#pragma unroll
                for (int jj = 0; jj < 4; ++jj)
#pragma unroll
                    for (int r = 0; r < 4; ++r)
                        sP[(wm + i * 16 + rw + r) * 76 + jj * 16 + cw] = acc[i][jj][r];
        }
        __syncthreads();                    // sP populated

        const int hg = (n0 >> 2) + p * 16 + hl;   // global hidden index
        const float b_i = bi[hg], b_f = bfv[hg], b_o = bo[hg], b_s = bs[hg];
#pragma unroll
        for (int k = 0; k < 8; ++k) {
            const int row = rb + 16 * k;          // 0..127
            float4 g = *(const float4*)(sP + row * 76 + hl * 4);
            const size_t oidx = (size_t)(m0 + row) * H_DIM + hg;
            float old = old_state[oidx];
            float ig = sigm_(g.x + b_i);
            float fg = sigm_(g.y + b_f);
            float og = sigm_(g.z + b_o);
            float ts = tanh_(g.w + b_s);
            out[oidx] = og * tanh_(fg * old + ig * ts);
        }
    }
}

// ---------------------------------------------------------------------------
extern "C" void kernel_launch(void* const* d_in, const int* in_sizes, int n_in,
                              void* d_out, int out_size, void* d_ws, size_t ws_size,
                              hipStream_t stream) {
    const float* x   = (const float*)d_in[0];
    const float* pt  = (const float*)d_in[1];
    const float* pl  = (const float*)d_in[2];
    const float* old = (const float*)d_in[3];
    const float* Wi  = (const float*)d_in[4];
    const float* bi  = (const float*)d_in[5];
    const float* Wf  = (const float*)d_in[6];
    const float* bf  = (const float*)d_in[7];
    const float* Wo  = (const float*)d_in[8];
    const float* bo  = (const float*)d_in[9];
    const float* Ws  = (const float*)d_in[10];
    const float* bs  = (const float*)d_in[11];
    float* out = (float*)d_out;

    char* ws = (char*)d_ws;
    unsigned short* Abf = (unsigned short*)(ws + A_OFF);
    unsigned short* Bbf = (unsigned short*)(ws + B_OFF);

    // 1) pack/convert: one block per destination row
    convert_kernel<<<M_DIM + N_DIM, 256, 0, stream>>>(x, pt, pl, Wi, Wf, Wo, Ws, Abf, Bbf);

    // 2) fused GEMM + gates, XCD-swizzled 1-D grid
    gemm_fused<<<512, 256, 0, stream>>>(Abf, Bbf, old, bi, bf, bo, bs, out);
}

// Round 5
// 234.076 us; speedup vs baseline: 1.3800x; 1.3800x over previous
//
#include <hip/hip_runtime.h>
#include <stdint.h>
#include <stddef.h>

#define M_DIM 2048
#define N_DIM 4096
#define K_DIM 4352
#define H_DIM 1024
#define X_DIM 2304

// workspace layout (bytes)
#define A_OFF 0u
#define B_OFF 17825792u                 // 2048*4352*2

typedef __bf16 bf16x8 __attribute__((ext_vector_type(8)));
typedef float f32x4 __attribute__((ext_vector_type(4)));

__device__ __forceinline__ unsigned short f32_to_bf16(float f) {
    unsigned u = __float_as_uint(f);
    u += 0x7FFFu + ((u >> 16) & 1u);     // round-to-nearest-even
    return (unsigned short)(u >> 16);
}

__device__ __forceinline__ float sigm_(float x) { return 1.f / (1.f + __expf(-x)); }
__device__ __forceinline__ float tanh_(float x) {
    x = fminf(15.f, fmaxf(-15.f, x));
    float e = __expf(2.f * x);
    return (e - 1.f) / (e + 1.f);
}

// ---------------------------------------------------------------------------
// Kernel 1: pack z = [x | prev_time | prev_layer] -> A (rows 0..2047) and
// W_all gate-INTERLEAVED -> B: source row n (g = n>>10, h = n&1023) goes to
// B row n' = h*4 + g. bf16, K-contiguous, 16B stores.
// ---------------------------------------------------------------------------
__global__ __launch_bounds__(256) void convert_kernel(
    const float* __restrict__ x, const float* __restrict__ pt,
    const float* __restrict__ pl,
    const float* __restrict__ Wi, const float* __restrict__ Wf,
    const float* __restrict__ Wo, const float* __restrict__ Ws,
    unsigned short* __restrict__ Abf, unsigned short* __restrict__ Bbf)
{
    const int row = blockIdx.x;                  // 0..6143
    const float* srow = nullptr;
    unsigned short* drow;
    if (row < M_DIM) {
        drow = Abf + (size_t)row * K_DIM;
    } else {
        int n = row - M_DIM;                      // 0..4095
        int g = n >> 10, h = n & 1023;
        const float* W = (g == 0) ? Wi : (g == 1) ? Wf : (g == 2) ? Wo : Ws;
        srow = W + (size_t)h * K_DIM;
        drow = Bbf + (size_t)(h * 4 + g) * K_DIM;
    }

    for (int c8 = threadIdx.x; c8 < K_DIM / 8; c8 += 256) {
        int col = c8 * 8;
        const float* s;
        if (row < M_DIM) {
            // boundaries 2304, 3328 are multiples of 8: chunks never straddle
            if (col < X_DIM)              s = x  + (size_t)row * X_DIM + col;
            else if (col < X_DIM + H_DIM) s = pt + (size_t)row * H_DIM + (col - X_DIM);
            else                          s = pl + (size_t)row * H_DIM + (col - X_DIM - H_DIM);
        } else {
            s = srow + col;
        }
        float4 v0 = ((const float4*)s)[0];
        float4 v1 = ((const float4*)s)[1];
        union { unsigned short h[8]; uint4 u; } r;
        r.h[0] = f32_to_bf16(v0.x); r.h[1] = f32_to_bf16(v0.y);
        r.h[2] = f32_to_bf16(v0.z); r.h[3] = f32_to_bf16(v0.w);
        r.h[4] = f32_to_bf16(v1.x); r.h[5] = f32_to_bf16(v1.y);
        r.h[6] = f32_to_bf16(v1.z); r.h[7] = f32_to_bf16(v1.w);
        *(uint4*)(drow + col) = r.u;
    }
}

// ---------------------------------------------------------------------------
// Kernel 2: fused GEMM + gates. 128x128 tile, BK=64, 4 waves, 64x64/wave,
// 4x4 mfma_f32_16x16x32_bf16. XOR-swizzled LDS (conflict-free, round 3).
// NEW: 2-stage LDS double buffer, ONE barrier per K-iter. Loads for tile
// kt+1 are issued AFTER the barrier (so the barrier's vmcnt(0) drain only
// waits on loads that flew across the whole previous compute phase).
// Epilogue fused via sP aliased over buf0.
// ---------------------------------------------------------------------------
__global__ __launch_bounds__(256) void gemm_fused(
    const unsigned short* __restrict__ A,   // [M_DIM, K_DIM] bf16
    const unsigned short* __restrict__ B,   // [N_DIM, K_DIM] bf16, gate-interleaved
    const float* __restrict__ old_state,    // [2048, 1024]
    const float* __restrict__ bi, const float* __restrict__ bfv,
    const float* __restrict__ bo, const float* __restrict__ bs,
    float* __restrict__ out)                // [2048, 1024]
{
    // buf p at p*32768: sA = +0 (16 KB), sB = +16384 (16 KB). Total 64 KB.
    // sP (128*76*4 = 38912 B) aliases buf0 + 6 KB of buf1 during epilogue.
    __shared__ __align__(16) char smem[65536];
    float* sP = (float*)smem;

    const int tid  = threadIdx.x;
    const int lane = tid & 63;
    const int wave = tid >> 6;              // 0..3
    const int wm = (wave >> 1) * 64;
    const int wn = (wave & 1) * 64;

    // XCD-aware decode: xcd b&7 owns n-tiles 4*xcd..4*xcd+3
    const int b   = blockIdx.x;             // 0..511
    const int xcd = b & 7;
    const int j   = b >> 3;                 // 0..63
    const int n0  = (xcd * 4 + (j & 3)) * 128;
    const int m0  = (j >> 2) * 128;

    // staging: lane deposits 16B at slot (i*256 + wave*64 + lane);
    // logical row = i*32 + wave*8 + (lane>>3), swizzled source col:
    const int srow = wave * 8 + (lane >> 3);
    const int c8s  = ((lane & 7) ^ (lane >> 3)) * 8;

    // fragment coords: frag[m|n = lane&15][k = (lane>>4)*8 + t]
    const int fr  = lane & 15;
    const int sw  = fr & 7;                 // row-swizzle key for reads
    const int kb0 = lane >> 4;              // k-block base

    f32x4 acc[4][4];
#pragma unroll
    for (int i = 0; i < 4; ++i)
#pragma unroll
        for (int jj = 0; jj < 4; ++jj) acc[i][jj] = (f32x4){0.f, 0.f, 0.f, 0.f};

    const unsigned short* Aw = A + (size_t)(m0 + srow) * K_DIM + c8s;
    const unsigned short* Bw = B + (size_t)(n0 + srow) * K_DIM + c8s;

    auto stage = [&](int kt, int bufOff) {
#pragma unroll
        for (int i = 0; i < 4; ++i) {
            __builtin_amdgcn_global_load_lds(
                (const __attribute__((address_space(1))) unsigned*)(Aw + (size_t)i * 32 * K_DIM + kt),
                (__attribute__((address_space(3))) unsigned*)(smem + bufOff + i * 4096 + wave * 1024),
                16, 0, 0);
            __builtin_amdgcn_global_load_lds(
                (const __attribute__((address_space(1))) unsigned*)(Bw + (size_t)i * 32 * K_DIM + kt),
                (__attribute__((address_space(3))) unsigned*)(smem + bufOff + 16384 + i * 4096 + wave * 1024),
                16, 0, 0);
        }
    };

    auto compute = [&](int bufOff) {
        const unsigned short* sA = (const unsigned short*)(smem + bufOff);
        const unsigned short* sB = (const unsigned short*)(smem + bufOff + 16384);
#pragma unroll
        for (int kk = 0; kk < 64; kk += 32) {
            const int kb = kk / 8 + kb0;    // logical k-block 0..7
            bf16x8 af[4], bfr[4];
#pragma unroll
            for (int i = 0; i < 4; ++i) {
                const int ra  = wm + i * 16 + fr;
                const int rb_ = wn + i * 16 + fr;
                af[i]  = *(const bf16x8*)(sA + (ra  * 8 + (kb ^ sw)) * 8);
                bfr[i] = *(const bf16x8*)(sB + (rb_ * 8 + (kb ^ sw)) * 8);
            }
#pragma unroll
            for (int i = 0; i < 4; ++i)
#pragma unroll
                for (int jj = 0; jj < 4; ++jj)
                    acc[i][jj] = __builtin_amdgcn_mfma_f32_16x16x32_bf16(
                        af[i], bfr[jj], acc[i][jj], 0, 0, 0);
        }
    };

    // prologue: tile 0 -> buf0
    stage(0, 0);

    // K_DIM = 68 * 64; unrolled x2 so buffer offsets are compile-time
    for (int kt = 0; kt < K_DIM; kt += 128) {
        __syncthreads();                    // drains buf0 loads; buf1 readers done
        if (kt + 64 < K_DIM) stage(kt + 64, 32768);
        compute(0);
        __syncthreads();                    // drains buf1 loads; buf0 readers done
        if (kt + 128 < K_DIM) stage(kt + 128, 0);
        compute(32768);
    }

    // ---- fused epilogue: two half-passes over n --------------------------
    // C/D layout: col = lane&15, row = (lane>>4)*4 + reg
    const int cw = lane & 15;
    const int rw = (lane >> 4) * 4;
    const int hl = tid & 15;                // h within pass
    const int rb = tid >> 4;                // 0..15

    for (int p = 0; p < 2; ++p) {
        __syncthreads();                    // K-loop readers / pass p-1 done
        if ((wave & 1) == p) {              // waves owning n-half p write
#pragma unroll
            for (int i = 0; i < 4; ++i)
#pragma unroll
                for (int jj = 0; jj < 4; ++jj)
#pragma unroll
                    for (int r = 0; r < 4; ++r)
                        sP[(wm + i * 16 + rw + r) * 76 + jj * 16 + cw] = acc[i][jj][r];
        }
        __syncthreads();                    // sP populated

        const int hg = (n0 >> 2) + p * 16 + hl;   // global hidden index
        const float b_i = bi[hg], b_f = bfv[hg], b_o = bo[hg], b_s = bs[hg];
#pragma unroll
        for (int k = 0; k < 8; ++k) {
            const int row = rb + 16 * k;          // 0..127
            float4 g = *(const float4*)(sP + row * 76 + hl * 4);
            const size_t oidx = (size_t)(m0 + row) * H_DIM + hg;
            float old = old_state[oidx];
            float ig = sigm_(g.x + b_i);
            float fg = sigm_(g.y + b_f);
            float og = sigm_(g.z + b_o);
            float ts = tanh_(g.w + b_s);
            out[oidx] = og * tanh_(fg * old + ig * ts);
        }
    }
}

// ---------------------------------------------------------------------------
extern "C" void kernel_launch(void* const* d_in, const int* in_sizes, int n_in,
                              void* d_out, int out_size, void* d_ws, size_t ws_size,
                              hipStream_t stream) {
    const float* x   = (const float*)d_in[0];
    const float* pt  = (const float*)d_in[1];
    const float* pl  = (const float*)d_in[2];
    const float* old = (const float*)d_in[3];
    const float* Wi  = (const float*)d_in[4];
    const float* bi  = (const float*)d_in[5];
    const float* Wf  = (const float*)d_in[6];
    const float* bf  = (const float*)d_in[7];
    const float* Wo  = (const float*)d_in[8];
    const float* bo  = (const float*)d_in[9];
    const float* Ws  = (const float*)d_in[10];
    const float* bs  = (const float*)d_in[11];
    float* out = (float*)d_out;

    char* ws = (char*)d_ws;
    unsigned short* Abf = (unsigned short*)(ws + A_OFF);
    unsigned short* Bbf = (unsigned short*)(ws + B_OFF);

    // 1) pack/convert: one block per destination row
    convert_kernel<<<M_DIM + N_DIM, 256, 0, stream>>>(x, pt, pl, Wi, Wf, Wo, Ws, Abf, Bbf);

    // 2) fused GEMM + gates, XCD-swizzled 1-D grid
    gemm_fused<<<512, 256, 0, stream>>>(Abf, Bbf, old, bi, bf, bo, bs, out);
}